// Round 5
// baseline (164.136 us; speedup 1.0000x reference)
//
#include <hip/hip_runtime.h>
#include <hip/hip_bf16.h>
#include <math.h>

#define NVOX 262144   // 64^3
#define BIGF 1e8f
#define GRID_A 1024   // stats/probs blocks
#define GRID_B 768    // EDT W+H blocks (b*192 + d*3 + cm)
#define GRID_K2 768   // EDT D + sdf blocks (combo*64 + h)

// ---- helpers ----
__device__ __forceinline__ unsigned short f2bf(float x) {
    __hip_bfloat16 h = __float2bfloat16(x);
    return *reinterpret_cast<unsigned short*>(&h);
}
__device__ __forceinline__ float bf2f(unsigned short u) {
    __hip_bfloat16 h = *reinterpret_cast<__hip_bfloat16*>(&u);
    return __bfloat162float(h);
}
// squared distance (u16, 0xFFFF = +inf) from lane w to nearest set bit of mask
__device__ __forceinline__ unsigned short dist2_u16(unsigned long long mask, int w) {
    if (mask == 0ull) return 0xFFFFu;
    unsigned long long mr = mask >> w;          // bits k >= w
    unsigned long long ml = mask << (63 - w);   // bits k <= w
    int dr = mr ? __builtin_ctzll(mr) : 127;
    int dl = ml ? __builtin_clzll(ml) : 127;
    int dd = dr < dl ? dr : dl;
    return (unsigned short)(dd * dd);
}

// =====================================================================
// K1: fused. Blocks [0,1024): streaming softmax stats + bf16 probsT.
//     Blocks [1024,1792): per-(b,d,class) ballot EDT pass-1 (W) +
//     early-exit pass-2 (H) in LDS, u16 planes to bufA.
// Layouts: probsT[combo][h][d][w] bf16; bufA[combo+12v][h][d][w] u16.
// =====================================================================
__global__ __launch_bounds__(256) void K1_fused(
    const float* __restrict__ preds, const int* __restrict__ targets,
    unsigned short* __restrict__ bufA, unsigned short* __restrict__ probsT,
    float* __restrict__ part_stats, int* __restrict__ counter) {
    __shared__ float tO[64 * 65];
    __shared__ float tI[64 * 65];
    __shared__ float sred[4 * 13];
    int bid = blockIdx.x;
    int t = threadIdx.x, lane = t & 63, wid = t >> 6;

    if (bid < GRID_A) {
        // ---------- path A: streaming stats + probs ----------
        if (bid == 0 && t == 0) *counter = 0;   // reset last-block counter for K2
        int b = bid >> 8, seg = bid & 255;
        size_t vbase = (size_t)seg * 1024 + 4 * t;
        const float* p = preds + (size_t)(b * 4) * NVOX + vbase;
        float4 x0 = *(const float4*)(p);
        float4 x1 = *(const float4*)(p + NVOX);
        float4 x2 = *(const float4*)(p + 2 * NVOX);
        float4 x3 = *(const float4*)(p + 3 * NVOX);
        int4 tv4 = *(const int4*)(targets + (size_t)b * NVOX + vbase);

        float q[13];
        #pragma unroll
        for (int k = 0; k < 13; ++k) q[k] = 0.0f;
        unsigned short pb[3][4];

        #pragma unroll
        for (int j = 0; j < 4; ++j) {
            float a0 = (&x0.x)[j], a1 = (&x1.x)[j], a2 = (&x2.x)[j], a3 = (&x3.x)[j];
            int tv = (&tv4.x)[j];
            float m  = fmaxf(fmaxf(a0, a1), fmaxf(a2, a3));
            float e0 = expf(a0 - m), e1 = expf(a1 - m), e2 = expf(a2 - m), e3 = expf(a3 - m);
            float ssum = e0 + e1 + e2 + e3;
            float inv  = 1.0f / ssum;
            float p0 = e0 * inv, p1 = e1 * inv, p2 = e2 * inv, p3 = e3 * inv;
            float xt = (tv == 0) ? a0 : (tv == 1) ? a1 : (tv == 2) ? a2 : a3;
            q[12] += -(xt - m - logf(ssum));
            q[4] += p0; q[5] += p1; q[6] += p2; q[7] += p3;
            if (tv == 0)      { q[0] += p0; q[8]  += 1.0f; }
            else if (tv == 1) { q[1] += p1; q[9]  += 1.0f; }
            else if (tv == 2) { q[2] += p2; q[10] += 1.0f; }
            else              { q[3] += p3; q[11] += 1.0f; }
            pb[0][j] = f2bf(p1); pb[1][j] = f2bf(p2); pb[2][j] = f2bf(p3);
        }

        int v0 = (int)vbase;
        int d = v0 >> 12, h = (v0 >> 6) & 63, w0 = v0 & 63;
        size_t poff = (size_t)h * 4096 + d * 64 + w0;
        #pragma unroll
        for (int c = 0; c < 3; ++c) {
            ushort4 u = make_ushort4(pb[c][0], pb[c][1], pb[c][2], pb[c][3]);
            *(ushort4*)(probsT + (size_t)(b * 3 + c) * NVOX + poff) = u;
        }

        #pragma unroll
        for (int k = 0; k < 13; ++k) {
            float x = q[k];
            #pragma unroll
            for (int o = 32; o > 0; o >>= 1) x += __shfl_down(x, o);
            if (lane == 0) sred[wid * 13 + k] = x;
        }
        __syncthreads();
        if (t < 13) {
            float s = sred[t] + sred[13 + t] + sred[26 + t] + sred[39 + t];
            part_stats[t * 1024 + bid] = s;
        }
    } else {
        // ---------- path B: EDT pass-1 (W, ballot) + pass-2 (H, early-exit) ----------
        int blk = bid - GRID_A;
        int cm = blk % 3;
        int bd = blk / 3;            // b*64 + d
        int d = bd & 63, b = bd >> 6;
        int c = cm + 1;
        const int* tg = targets + (size_t)b * NVOX + (size_t)d * 4096;

        #pragma unroll
        for (int i = 0; i < 16; ++i) {
            int e = t + 256 * i;
            int h = wid + 4 * i;
            int tv = tg[e];
            unsigned long long mask = __ballot(tv == c);
            unsigned short o  = dist2_u16(mask, lane);
            unsigned short ii = dist2_u16(~mask, lane);
            tO[h * 65 + lane] = (o  == 0xFFFFu) ? BIGF : (float)o;
            tI[h * 65 + lane] = (ii == 0xFFFFu) ? BIGF : (float)ii;
        }
        __syncthreads();

        // pass-2 along H: wave owns 16 cols w = wid*16+r; lane = h. Early-exit.
        for (int r = 0; r < 16; ++r) {
            int w = wid * 16 + r;
            {
                float best = tO[lane * 65 + w];
                for (int dk = 1; dk < 64; ++dk) {
                    float d2 = (float)(dk * dk);
                    if (__all(d2 >= best)) break;
                    int hl = lane - dk; hl = hl < 0 ? 0 : hl;
                    int hr = lane + dk; hr = hr > 63 ? 63 : hr;
                    best = fminf(fminf(best, tO[hl * 65 + w] + d2), tO[hr * 65 + w] + d2);
                }
                tO[lane * 65 + w] = best;   // wave-lockstep: safe in-place
            }
            {
                float best = tI[lane * 65 + w];
                for (int dk = 1; dk < 64; ++dk) {
                    float d2 = (float)(dk * dk);
                    if (__all(d2 >= best)) break;
                    int hl = lane - dk; hl = hl < 0 ? 0 : hl;
                    int hr = lane + dk; hr = hr > 63 ? 63 : hr;
                    best = fminf(fminf(best, tI[hl * 65 + w] + d2), tI[hr * 65 + w] + d2);
                }
                tI[lane * 65 + w] = best;
            }
        }
        __syncthreads();

        int combo = b * 3 + cm;
        size_t oO = (size_t)combo * NVOX + (size_t)d * 64;
        size_t oI = (size_t)(combo + 12) * NVOX + (size_t)d * 64;
        #pragma unroll
        for (int i = 0; i < 16; ++i) {
            int h = wid + 4 * i;
            float vo = tO[h * 65 + lane];
            float vi = tI[h * 65 + lane];
            bufA[oO + (size_t)h * 4096 + lane] = (vo >= 1e7f) ? 0xFFFFu : (unsigned short)vo;
            bufA[oI + (size_t)h * 4096 + lane] = (vi >= 1e7f) ? 0xFFFFu : (unsigned short)vi;
        }
    }
}

// =====================================================================
// K2: EDT pass-3 (D, early-exit) + sdf*prob reduce; LAST block does the
// f64 combine (guards + dice + ce + boundary) and writes the scalar.
// grid = 768 (combo*64 + h), 512 thr.
// =====================================================================
__global__ __launch_bounds__(512) void K2_fused(
    const unsigned short* __restrict__ bufA, const unsigned short* __restrict__ probsT,
    const float* __restrict__ part_stats, float* __restrict__ part_bound,
    int* __restrict__ counter, float* __restrict__ out) {
    __shared__ float pl[2][64 * 65];
    __shared__ float sredb[8];
    __shared__ int amLast;
    int blk = blockIdx.x;
    int combo = blk >> 6, h = blk & 63;
    int t = threadIdx.x, lane = t & 63, wid = t >> 6;

    for (int v = 0; v < 2; ++v) {
        const unsigned short* src = bufA + (size_t)(combo + 12 * v) * NVOX + (size_t)h * 4096;
        #pragma unroll
        for (int i = 0; i < 8; ++i) {
            int e = t + 512 * i;                     // e = d*64 + w
            unsigned short u = src[e];
            pl[v][e + (e >> 6)] = (u == 0xFFFFu) ? BIGF : (float)u;   // lds[d*65+w]
        }
    }
    __syncthreads();

    // pass along D: wave owns cols w = wid*8+r; lane = d. Early-exit.
    for (int v = 0; v < 2; ++v) {
        for (int r = 0; r < 8; ++r) {
            int w = wid * 8 + r;
            float* col = &pl[v][w];
            float best = col[lane * 65];
            for (int dk = 1; dk < 64; ++dk) {
                float d2 = (float)(dk * dk);
                if (__all(d2 >= best)) break;
                int dl = lane - dk; dl = dl < 0 ? 0 : dl;
                int dr = lane + dk; dr = dr > 63 ? 63 : dr;
                best = fminf(fminf(best, col[dl * 65] + d2), col[dr * 65] + d2);
            }
            col[lane * 65] = best;
        }
    }
    __syncthreads();

    const unsigned short* pp = probsT + (size_t)combo * NVOX + (size_t)h * 4096;
    float acc = 0.0f;
    #pragma unroll
    for (int i = 0; i < 8; ++i) {
        int e = t + 512 * i;
        int li = e + (e >> 6);
        float sdf = sqrtf(pl[0][li]) - sqrtf(pl[1][li]);
        acc += sdf * bf2f(pp[e]);
    }
    #pragma unroll
    for (int o = 32; o > 0; o >>= 1) acc += __shfl_down(acc, o);
    if (lane == 0) sredb[wid] = acc;
    __syncthreads();
    if (t == 0) {
        float s = 0.0f;
        for (int j = 0; j < 8; ++j) s += sredb[j];
        part_bound[blk] = s;
    }

    // ---- last-block combine ----
    __threadfence();
    if (t == 0) amLast = (atomicAdd(counter, 1) == GRID_K2 - 1);
    __syncthreads();
    if (!amLast) return;
    __threadfence();

    __shared__ float csred[13 * 8];
    __shared__ double S[52];
    __shared__ double BND[12];
    // reduce part_stats: 13 rows x 1024 (blk = b*256+seg); 128 threads per b
    for (int k = 0; k < 13; ++k) {
        int b = t >> 7, s = t & 127;
        float v = part_stats[k * 1024 + b * 256 + s]
                + part_stats[k * 1024 + b * 256 + s + 128];
        #pragma unroll
        for (int o = 32; o > 0; o >>= 1) v += __shfl_down(v, o);
        if (lane == 0) csred[k * 8 + wid] = v;   // wave wid covers b = wid>>1
    }
    __syncthreads();
    if (t < 52) {
        int k = t >> 2, b = t & 3;
        S[k * 4 + b] = (double)csred[k * 8 + b * 2] + (double)csred[k * 8 + b * 2 + 1];
    }
    if (wid < 6) {               // two combos per wave
        float v1 = part_bound[wid * 64 + lane];
        float v2 = part_bound[(wid + 6) * 64 + lane];
        #pragma unroll
        for (int o = 32; o > 0; o >>= 1) { v1 += __shfl_down(v1, o); v2 += __shfl_down(v2, o); }
        if (lane == 0) { BND[wid] = (double)v1; BND[wid + 6] = (double)v2; }
    }
    __syncthreads();
    if (t == 0) {
        const double NV = (double)NVOX;
        double dice_sum = 0.0;
        for (int b = 0; b < 4; ++b)
            for (int c = 0; c < 4; ++c) {
                double inter = S[c * 4 + b];
                double un    = S[(4 + c) * 4 + b] + S[(8 + c) * 4 + b];
                dice_sum += (2.0 * inter + 1e-5) / (un + 1e-5);
            }
        double l_dice = 1.0 - dice_sum / 16.0;
        double l_ce = (S[48] + S[49] + S[50] + S[51]) / (4.0 * NV);
        double lb = 0.0;
        for (int cb = 0; cb < 12; ++cb) {
            int b = cb / 3, c = cb % 3 + 1;
            double cnt = S[(8 + c) * 4 + b];
            double s;
            if (cnt == 0.0)      s =  S[(4 + c) * 4 + b];   // sdf == +1 everywhere
            else if (cnt == NV)  s = -S[(4 + c) * 4 + b];   // sdf == -1 everywhere
            else                 s =  BND[cb];
            lb += s / NV;
        }
        lb /= 12.0;
        out[0] = (float)(l_dice + l_ce + 0.01 * lb);
    }
}

extern "C" void kernel_launch(void* const* d_in, const int* in_sizes, int n_in,
                              void* d_out, int out_size, void* d_ws, size_t ws_size,
                              hipStream_t stream) {
    const float* preds   = (const float*)d_in[0];
    const int*   targets = (const int*)d_in[1];
    float* out = (float*)d_out;

    // workspace: bufA u16 (12.6 MB) | probsT bf16 (6.3 MB) | partials | counter
    unsigned short* bufA   = (unsigned short*)d_ws;
    unsigned short* probsT = bufA + (size_t)24 * NVOX;
    float* part_stats = (float*)(probsT + (size_t)12 * NVOX);
    float* part_bound = part_stats + 13 * 1024;
    int*   counter    = (int*)(part_bound + GRID_K2);

    K1_fused<<<GRID_A + GRID_B, 256, 0, stream>>>(preds, targets, bufA, probsT,
                                                  part_stats, counter);
    K2_fused<<<GRID_K2, 512, 0, stream>>>(bufA, probsT, part_stats, part_bound,
                                          counter, out);
}

// Round 6
// 48.824 us; speedup vs baseline: 3.3618x; 3.3618x over previous
//
#include <hip/hip_runtime.h>
#include <hip/hip_bf16.h>
#include <math.h>

#define NVOX 262144   // 64^3
#define BIGF 1e8f
#define GRID_A 1024   // stats/probs blocks
#define GRID_B 768    // EDT W+H blocks (b*192 + d*3 + cm)
#define GRID_K2 768   // EDT D + sdf blocks (combo*64 + h)

// ---- helpers ----
__device__ __forceinline__ unsigned short f2bf(float x) {
    __hip_bfloat16 h = __float2bfloat16(x);
    return *reinterpret_cast<unsigned short*>(&h);
}
__device__ __forceinline__ float bf2f(unsigned short u) {
    __hip_bfloat16 h = *reinterpret_cast<__hip_bfloat16*>(&u);
    return __bfloat162float(h);
}
// squared distance (u16, 0xFFFF = +inf) from lane w to nearest set bit of mask
__device__ __forceinline__ unsigned short dist2_u16(unsigned long long mask, int w) {
    if (mask == 0ull) return 0xFFFFu;
    unsigned long long mr = mask >> w;          // bits k >= w
    unsigned long long ml = mask << (63 - w);   // bits k <= w
    int dr = mr ? __builtin_ctzll(mr) : 127;
    int dl = ml ? __builtin_clzll(ml) : 127;
    int dd = dr < dl ? dr : dl;
    return (unsigned short)(dd * dd);
}

// =====================================================================
// K1: fused block-split. Blocks [0,1024): streaming softmax stats + bf16
// probsT. Blocks [1024,1792): per-(b,d,class) ballot EDT pass-1 (W) +
// early-exit pass-2 (H) in LDS -> u16 planes in bufA.
// Layouts: probsT[combo][h][d][w] bf16; bufA[combo+12v][h][d][w] u16.
// NO fences, NO atomics (round-5 post-mortem: agent-scope fences from many
// blocks cause L2 writeback storms on gfx950 -> 27x kernel slowdown).
// =====================================================================
__global__ __launch_bounds__(256) void K1_fused(
    const float* __restrict__ preds, const int* __restrict__ targets,
    unsigned short* __restrict__ bufA, unsigned short* __restrict__ probsT,
    float* __restrict__ part_stats) {
    __shared__ float tO[64 * 65];
    __shared__ float tI[64 * 65];
    __shared__ float sred[4 * 13];
    int bid = blockIdx.x;
    int t = threadIdx.x, lane = t & 63, wid = t >> 6;

    if (bid < GRID_A) {
        // ---------- path A: streaming stats + probs ----------
        int b = bid >> 8, seg = bid & 255;
        size_t vbase = (size_t)seg * 1024 + 4 * t;
        const float* p = preds + (size_t)(b * 4) * NVOX + vbase;
        float4 x0 = *(const float4*)(p);
        float4 x1 = *(const float4*)(p + NVOX);
        float4 x2 = *(const float4*)(p + 2 * NVOX);
        float4 x3 = *(const float4*)(p + 3 * NVOX);
        int4 tv4 = *(const int4*)(targets + (size_t)b * NVOX + vbase);

        float q[13];
        #pragma unroll
        for (int k = 0; k < 13; ++k) q[k] = 0.0f;
        unsigned short pb[3][4];

        #pragma unroll
        for (int j = 0; j < 4; ++j) {
            float a0 = (&x0.x)[j], a1 = (&x1.x)[j], a2 = (&x2.x)[j], a3 = (&x3.x)[j];
            int tv = (&tv4.x)[j];
            float m  = fmaxf(fmaxf(a0, a1), fmaxf(a2, a3));
            float e0 = expf(a0 - m), e1 = expf(a1 - m), e2 = expf(a2 - m), e3 = expf(a3 - m);
            float ssum = e0 + e1 + e2 + e3;
            float inv  = 1.0f / ssum;
            float p0 = e0 * inv, p1 = e1 * inv, p2 = e2 * inv, p3 = e3 * inv;
            float xt = (tv == 0) ? a0 : (tv == 1) ? a1 : (tv == 2) ? a2 : a3;
            q[12] += -(xt - m - logf(ssum));
            q[4] += p0; q[5] += p1; q[6] += p2; q[7] += p3;
            if (tv == 0)      { q[0] += p0; q[8]  += 1.0f; }
            else if (tv == 1) { q[1] += p1; q[9]  += 1.0f; }
            else if (tv == 2) { q[2] += p2; q[10] += 1.0f; }
            else              { q[3] += p3; q[11] += 1.0f; }
            pb[0][j] = f2bf(p1); pb[1][j] = f2bf(p2); pb[2][j] = f2bf(p3);
        }

        int v0 = (int)vbase;
        int d = v0 >> 12, h = (v0 >> 6) & 63, w0 = v0 & 63;
        size_t poff = (size_t)h * 4096 + d * 64 + w0;
        #pragma unroll
        for (int c = 0; c < 3; ++c) {
            ushort4 u = make_ushort4(pb[c][0], pb[c][1], pb[c][2], pb[c][3]);
            *(ushort4*)(probsT + (size_t)(b * 3 + c) * NVOX + poff) = u;
        }

        #pragma unroll
        for (int k = 0; k < 13; ++k) {
            float x = q[k];
            #pragma unroll
            for (int o = 32; o > 0; o >>= 1) x += __shfl_down(x, o);
            if (lane == 0) sred[wid * 13 + k] = x;
        }
        __syncthreads();
        if (t < 13) {
            float s = sred[t] + sred[13 + t] + sred[26 + t] + sred[39 + t];
            part_stats[t * 1024 + bid] = s;
        }
    } else {
        // ---------- path B: EDT pass-1 (W, ballot) + pass-2 (H, early-exit) ----------
        int blk = bid - GRID_A;
        int cm = blk % 3;
        int bd = blk / 3;            // b*64 + d
        int d = bd & 63, b = bd >> 6;
        int c = cm + 1;
        const int* tg = targets + (size_t)b * NVOX + (size_t)d * 4096;

        #pragma unroll
        for (int i = 0; i < 16; ++i) {
            int e = t + 256 * i;
            int h = wid + 4 * i;
            int tv = tg[e];
            unsigned long long mask = __ballot(tv == c);
            unsigned short o  = dist2_u16(mask, lane);
            unsigned short ii = dist2_u16(~mask, lane);
            tO[h * 65 + lane] = (o  == 0xFFFFu) ? BIGF : (float)o;
            tI[h * 65 + lane] = (ii == 0xFFFFu) ? BIGF : (float)ii;
        }
        __syncthreads();

        // pass-2 along H: wave owns 16 cols w = wid*16+r; lane = h. Early-exit.
        for (int r = 0; r < 16; ++r) {
            int w = wid * 16 + r;
            {
                float best = tO[lane * 65 + w];
                for (int dk = 1; dk < 64; ++dk) {
                    float d2 = (float)(dk * dk);
                    if (__all(d2 >= best)) break;
                    int hl = lane - dk; hl = hl < 0 ? 0 : hl;
                    int hr = lane + dk; hr = hr > 63 ? 63 : hr;
                    best = fminf(fminf(best, tO[hl * 65 + w] + d2), tO[hr * 65 + w] + d2);
                }
                tO[lane * 65 + w] = best;   // wave-lockstep: safe in-place
            }
            {
                float best = tI[lane * 65 + w];
                for (int dk = 1; dk < 64; ++dk) {
                    float d2 = (float)(dk * dk);
                    if (__all(d2 >= best)) break;
                    int hl = lane - dk; hl = hl < 0 ? 0 : hl;
                    int hr = lane + dk; hr = hr > 63 ? 63 : hr;
                    best = fminf(fminf(best, tI[hl * 65 + w] + d2), tI[hr * 65 + w] + d2);
                }
                tI[lane * 65 + w] = best;
            }
        }
        __syncthreads();

        int combo = b * 3 + cm;
        size_t oO = (size_t)combo * NVOX + (size_t)d * 64;
        size_t oI = (size_t)(combo + 12) * NVOX + (size_t)d * 64;
        #pragma unroll
        for (int i = 0; i < 16; ++i) {
            int h = wid + 4 * i;
            float vo = tO[h * 65 + lane];
            float vi = tI[h * 65 + lane];
            bufA[oO + (size_t)h * 4096 + lane] = (vo >= 1e7f) ? 0xFFFFu : (unsigned short)vo;
            bufA[oI + (size_t)h * 4096 + lane] = (vi >= 1e7f) ? 0xFFFFu : (unsigned short)vi;
        }
    }
}

// =====================================================================
// K2: EDT pass-3 (D, early-exit) + sdf*prob reduce -> one float per block.
// grid = 768 (combo*64 + h), 512 thr. All global accesses contiguous.
// =====================================================================
__global__ __launch_bounds__(512) void K2_edt3_sdf(
    const unsigned short* __restrict__ bufA, const unsigned short* __restrict__ probsT,
    float* __restrict__ part_bound) {
    __shared__ float pl[2][64 * 65];
    __shared__ float sredb[8];
    int blk = blockIdx.x;
    int combo = blk >> 6, h = blk & 63;
    int t = threadIdx.x, lane = t & 63, wid = t >> 6;

    for (int v = 0; v < 2; ++v) {
        const unsigned short* src = bufA + (size_t)(combo + 12 * v) * NVOX + (size_t)h * 4096;
        #pragma unroll
        for (int i = 0; i < 8; ++i) {
            int e = t + 512 * i;                     // e = d*64 + w
            unsigned short u = src[e];
            pl[v][e + (e >> 6)] = (u == 0xFFFFu) ? BIGF : (float)u;   // lds[d*65+w]
        }
    }
    __syncthreads();

    // pass along D: wave owns cols w = wid*8+r; lane = d. Early-exit.
    for (int v = 0; v < 2; ++v) {
        for (int r = 0; r < 8; ++r) {
            int w = wid * 8 + r;
            float* col = &pl[v][w];
            float best = col[lane * 65];
            for (int dk = 1; dk < 64; ++dk) {
                float d2 = (float)(dk * dk);
                if (__all(d2 >= best)) break;
                int dl = lane - dk; dl = dl < 0 ? 0 : dl;
                int dr = lane + dk; dr = dr > 63 ? 63 : dr;
                best = fminf(fminf(best, col[dl * 65] + d2), col[dr * 65] + d2);
            }
            col[lane * 65] = best;
        }
    }
    __syncthreads();

    const unsigned short* pp = probsT + (size_t)combo * NVOX + (size_t)h * 4096;
    float acc = 0.0f;
    #pragma unroll
    for (int i = 0; i < 8; ++i) {
        int e = t + 512 * i;
        int li = e + (e >> 6);
        float sdf = sqrtf(pl[0][li]) - sqrtf(pl[1][li]);
        acc += sdf * bf2f(pp[e]);
    }
    #pragma unroll
    for (int o = 32; o > 0; o >>= 1) acc += __shfl_down(acc, o);
    if (lane == 0) sredb[wid] = acc;
    __syncthreads();
    if (t == 0) {
        float s = 0.0f;
        for (int j = 0; j < 8; ++j) s += sredb[j];
        part_bound[blk] = s;
    }
}

// =====================================================================
// K3: single block, latency-optimized: ALL global loads issued up-front
// into registers (ILP), then shfl/LDS reduce, f64 combine with guards.
// =====================================================================
__global__ __launch_bounds__(1024) void K3_final(
    const float* __restrict__ part_stats, const float* __restrict__ part_bound,
    float* __restrict__ out) {
    __shared__ float sred[13 * 16];
    __shared__ float bred[12];
    __shared__ double S[52];
    int t = threadIdx.x, lane = t & 63, wid = t >> 6;

    // issue all loads first (independent -> pipelined)
    float v[13];
    #pragma unroll
    for (int k = 0; k < 13; ++k) v[k] = part_stats[k * 1024 + t];
    float bv = (wid < 12) ? part_bound[wid * 64 + lane] : 0.0f;

    #pragma unroll
    for (int k = 0; k < 13; ++k) {
        float x = v[k];
        #pragma unroll
        for (int o = 32; o > 0; o >>= 1) x += __shfl_down(x, o);
        if (lane == 0) sred[k * 16 + wid] = x;
    }
    #pragma unroll
    for (int o = 32; o > 0; o >>= 1) bv += __shfl_down(bv, o);
    if (lane == 0 && wid < 12) bred[wid] = bv;
    __syncthreads();

    if (t < 52) {   // k = t>>2, b = t&3; block ids were b*256+seg -> waves 4b..4b+3
        int k = t >> 2, b = t & 3;
        S[k * 4 + b] = (double)sred[k * 16 + b * 4]     + (double)sred[k * 16 + b * 4 + 1]
                     + (double)sred[k * 16 + b * 4 + 2] + (double)sred[k * 16 + b * 4 + 3];
    }
    __syncthreads();
    if (t == 0) {
        const double NV = (double)NVOX;
        double dice_sum = 0.0;
        for (int b = 0; b < 4; ++b)
            for (int c = 0; c < 4; ++c) {
                double inter = S[c * 4 + b];
                double un    = S[(4 + c) * 4 + b] + S[(8 + c) * 4 + b];
                dice_sum += (2.0 * inter + 1e-5) / (un + 1e-5);
            }
        double l_dice = 1.0 - dice_sum / 16.0;
        double l_ce = (S[48] + S[49] + S[50] + S[51]) / (4.0 * NV);
        double lb = 0.0;
        for (int cb = 0; cb < 12; ++cb) {
            int b = cb / 3, c = cb % 3 + 1;
            double cnt = S[(8 + c) * 4 + b];
            double s;
            if (cnt == 0.0)      s =  S[(4 + c) * 4 + b];   // sdf == +1 everywhere
            else if (cnt == NV)  s = -S[(4 + c) * 4 + b];   // sdf == -1 everywhere
            else                 s =  (double)bred[cb];
            lb += s / NV;
        }
        lb /= 12.0;
        out[0] = (float)(l_dice + l_ce + 0.01 * lb);
    }
}

extern "C" void kernel_launch(void* const* d_in, const int* in_sizes, int n_in,
                              void* d_out, int out_size, void* d_ws, size_t ws_size,
                              hipStream_t stream) {
    const float* preds   = (const float*)d_in[0];
    const int*   targets = (const int*)d_in[1];
    float* out = (float*)d_out;

    // workspace: bufA u16 (12.6 MB) | probsT bf16 (6.3 MB) | partials (~56 KB)
    unsigned short* bufA   = (unsigned short*)d_ws;
    unsigned short* probsT = bufA + (size_t)24 * NVOX;
    float* part_stats = (float*)(probsT + (size_t)12 * NVOX);
    float* part_bound = part_stats + 13 * 1024;

    K1_fused<<<GRID_A + GRID_B, 256, 0, stream>>>(preds, targets, bufA, probsT, part_stats);
    K2_edt3_sdf<<<GRID_K2, 512, 0, stream>>>(bufA, probsT, part_bound);
    K3_final<<<1, 1024, 0, stream>>>(part_stats, part_bound, out);
}